// Round 1
// baseline (237.052 us; speedup 1.0000x reference)
//
#include <hip/hip_runtime.h>
#include <hip/hip_bf16.h>

// RDF with minimum-image PBC + Gaussian smearing, N=2048 atoms, 100 bins.
// Kernel 1: grid-stride over N*N pair indices; per-block LDS histogram
//           (float LDS atomics), full partial written to ws per block
//           (deterministic — no global float atomics).
// Kernel 2: one block reduces partials, normalizes, writes
//           d_out = [count(100) | bins(101) | rdf(100)].

#define N_ATOMS 2048
#define LOG2_N  11
#define NBINS   100
#define WK      10      // smear window: +-10 bin widths (exp(-50) ~ 2e-22, negligible)

__global__ __launch_bounds__(256) void rdf_pairs(
    const float* __restrict__ xyz,
    const float* __restrict__ cell,
    const float* __restrict__ offsets,
    float* __restrict__ partials,
    int nblocks)
{
    __shared__ float sx[N_ATOMS];
    __shared__ float sy[N_ATOMS];
    __shared__ float sz[N_ATOMS];
    __shared__ float soff[NBINS];
    __shared__ float hist[NBINS];

    const int tid = threadIdx.x;

    // Stage positions SoA into LDS (24 KB) — consecutive-lane j reads become
    // conflict-free stride-1 LDS reads in the pair loop.
    for (int a = tid; a < N_ATOMS; a += blockDim.x) {
        sx[a] = xyz[3 * a + 0];
        sy[a] = xyz[3 * a + 1];
        sz[a] = xyz[3 * a + 2];
    }
    if (tid < NBINS) {
        soff[tid] = offsets[tid];
        hist[tid] = 0.0f;
    }
    __syncthreads();

    const float cx = cell[0], cy = cell[1], cz = cell[2];
    const float hcx = 0.5f * cx, hcy = 0.5f * cy, hcz = 0.5f * cz;

    const float width = soff[1] - soff[0];
    const float invw  = 1.0f / width;
    const float coeff = -0.5f / (width * width);
    // CUTOFF_B = R_END + 0.5, R_END = offsets[NBINS-1] (linspace endpoint = 7.5)
    const float cutb  = soff[NBINS - 1] + 0.5f;
    const float cut2  = cutb * cutb;

    const int total = N_ATOMS * N_ATOMS;
    const int gsize = nblocks * 256;

    for (int p = blockIdx.x * 256 + tid; p < total; p += gsize) {
        const int i = p >> LOG2_N;
        const int j = p & (N_ATOMS - 1);

        // disp[i][j] = xyz[j] - xyz[i], minimum-image wrap (matches reference:
        // shift = -(d >= 0.5c) + (d < -0.5c), d += shift*c)
        float dx = sx[j] - sx[i];
        float dy = sy[j] - sy[i];
        float dz = sz[j] - sz[i];
        dx += (dx >= hcx) ? -cx : ((dx < -hcx) ? cx : 0.0f);
        dy += (dy >= hcy) ? -cy : ((dy < -hcy) ? cy : 0.0f);
        dz += (dz >= hcz) ? -cz : ((dz < -hcz) ? cz : 0.0f);

        const float dsq = dx * dx + dy * dy + dz * dz;
        if (dsq < cut2 && dsq != 0.0f) {
            const float dist = sqrtf(dsq);
            const int kc = (int)(dist * invw);
            int klo = kc - WK; if (klo < 0) klo = 0;
            int khi = kc + WK; if (khi > NBINS - 1) khi = NBINS - 1;
            for (int k = klo; k <= khi; ++k) {
                const float d = dist - soff[k];
                atomicAdd(&hist[k], __expf(coeff * d * d));
            }
        }
    }

    __syncthreads();
    if (tid < NBINS) {
        partials[blockIdx.x * NBINS + tid] = hist[tid];
    }
}

__global__ __launch_bounds__(128) void rdf_finalize(
    const float* __restrict__ partials,
    int nblocks,
    const float* __restrict__ bins,
    float* __restrict__ out)
{
    __shared__ float raw[NBINS];
    __shared__ float ssum[2];

    const int t = threadIdx.x;

    if (t < NBINS) {
        float s = 0.0f;
        for (int g = 0; g < nblocks; ++g) s += partials[g * NBINS + t];
        raw[t] = s;
    }
    __syncthreads();

    // total over all bins: 64-lane shuffle reduce, combine 2 waves via LDS
    float v = (t < NBINS) ? raw[t] : 0.0f;
    #pragma unroll
    for (int o = 32; o > 0; o >>= 1) v += __shfl_down(v, o);
    if ((t & 63) == 0) ssum[t >> 6] = v;
    __syncthreads();
    const float S = ssum[0] + ssum[1];

    if (t < NBINS) {
        const float cnt = raw[t] / S;
        out[t] = cnt;                              // count
        const float b0 = bins[t], b1 = bins[t + 1];
        const float R  = bins[NBINS];              // R_END = 7.5
        // rdf = cnt / (vol_bin / V) = cnt * R^3 / (b1^3 - b0^3)  (4pi/3 cancels)
        out[201 + t] = cnt * (R * R * R) / (b1 * b1 * b1 - b0 * b0 * b0);
    }
    if (t < NBINS + 1) {
        out[100 + t] = bins[t];                    // bins passthrough
    }
}

extern "C" void kernel_launch(void* const* d_in, const int* in_sizes, int n_in,
                              void* d_out, int out_size, void* d_ws, size_t ws_size,
                              hipStream_t stream) {
    const float* xyz     = (const float*)d_in[0];
    const float* cell    = (const float*)d_in[1];
    const float* bins    = (const float*)d_in[2];
    const float* offsets = (const float*)d_in[3];
    float* out      = (float*)d_out;
    float* partials = (float*)d_ws;

    int nblocks = 512;
    const int maxblocks = (int)(ws_size / (NBINS * sizeof(float)));
    if (nblocks > maxblocks) nblocks = maxblocks;
    if (nblocks < 1) nblocks = 1;

    rdf_pairs<<<nblocks, 256, 0, stream>>>(xyz, cell, offsets, partials, nblocks);
    rdf_finalize<<<1, 128, 0, stream>>>(partials, nblocks, bins, out);
}

// Round 2
// 72.716 us; speedup vs baseline: 3.2600x; 3.2600x over previous
//
#include <hip/hip_runtime.h>
#include <hip/hip_bf16.h>

// RDF with minimum-image PBC + Gaussian smearing, N=2048 atoms, 100 bins.
//
// Kernel 1 (rdf_pairs): grid-stride over N*N flat pair index, upper-triangle
//   only (j>i; the x2 weight cancels in count normalization). Per-wave LDS
//   float histograms (4x100) to cut atomic serialization. Gaussian smear over
//   +-5 bin widths via exact geometric recurrence (2 exps per pair, 2 muls
//   per bin). Partials written TRANSPOSED: partials[bin*nblocks + block].
//
// Kernel 2 (rdf_finalize): 1 block x 1024 threads; 8 chunks x 128 bins, each
//   thread sums nblocks/8 contiguous floats as float4 (coalesced, unrolled),
//   then LDS reduce + normalize. d_out = [count(100) | bins(101) | rdf(100)].

#define N_ATOMS 2048
#define LOG2_N  11
#define NBINS   100
#define WK      5       // +-5 bin widths: truncation exp(-12.5) ~ 4e-6 relative

__global__ __launch_bounds__(256) void rdf_pairs(
    const float* __restrict__ xyz,
    const float* __restrict__ cell,
    const float* __restrict__ offsets,
    float* __restrict__ partials,
    int nblocks)
{
    __shared__ float sx[N_ATOMS];
    __shared__ float sy[N_ATOMS];
    __shared__ float sz[N_ATOMS];
    __shared__ float soff[NBINS];
    __shared__ float hist[4][NBINS];   // per-wave private histograms

    const int tid = threadIdx.x;

    for (int a = tid; a < N_ATOMS; a += 256) {
        sx[a] = xyz[3 * a + 0];
        sy[a] = xyz[3 * a + 1];
        sz[a] = xyz[3 * a + 2];
    }
    if (tid < NBINS) {
        soff[tid] = offsets[tid];
        hist[0][tid] = 0.0f;
        hist[1][tid] = 0.0f;
        hist[2][tid] = 0.0f;
        hist[3][tid] = 0.0f;
    }
    __syncthreads();

    const float cx = cell[0], cy = cell[1], cz = cell[2];
    const float hcx = 0.5f * cx, hcy = 0.5f * cy, hcz = 0.5f * cz;

    const float width = soff[1] - soff[0];   // 7.5/99
    const float invw  = 1.0f / width;
    const float coeff = -0.5f / (width * width);
    const float cutb  = soff[NBINS - 1] + 0.5f;   // CUTOFF_B = R_END + 0.5 = 8.0
    const float cut2  = cutb * cutb;

    float* const hw = hist[tid >> 6];

    const int total = N_ATOMS * N_ATOMS;
    const int gsize = nblocks * 256;

    for (int p = blockIdx.x * 256 + tid; p < total; p += gsize) {
        const int i = p >> LOG2_N;
        const int j = p & (N_ATOMS - 1);
        if (j <= i) continue;   // wave spans 64 consecutive j in one row -> uniform skip

        float dx = sx[j] - sx[i];
        float dy = sy[j] - sy[i];
        float dz = sz[j] - sz[i];
        dx += (dx >= hcx) ? -cx : ((dx < -hcx) ? cx : 0.0f);
        dy += (dy >= hcy) ? -cy : ((dy < -hcy) ? cy : 0.0f);
        dz += (dz >= hcz) ? -cz : ((dz < -hcz) ? cz : 0.0f);

        const float dsq = dx * dx + dy * dy + dz * dz;
        if (dsq < cut2 && dsq != 0.0f) {
            const float dist = sqrtf(dsq);
            const int kc = (int)(dist * invw);
            int klo = kc - WK; if (klo < 0) klo = 0;
            int khi = kc + WK; if (khi > NBINS - 1) khi = NBINS - 1;
            if (klo > NBINS - 1) continue;   // dist near 8.0: contribution < 2e-8

            // geometric recurrence: g_{k+1} = g_k * r_k, r_{k+1} = r_k * e^-1
            // (exact: coeff = -0.5/w^2  =>  2*coeff*w^2 = -1)
            const float u0 = dist - soff[klo];
            float g = __expf(coeff * u0 * u0);
            float r = __expf(u0 * invw - 0.5f);
            for (int k = klo; k <= khi; ++k) {
                atomicAdd(&hw[k], g);
                g *= r;
                r *= 0.36787944117144233f;
            }
        }
    }

    __syncthreads();
    if (tid < NBINS) {
        const float s = hist[0][tid] + hist[1][tid] + hist[2][tid] + hist[3][tid];
        partials[tid * nblocks + blockIdx.x] = s;   // transposed for finalize float4
    }
}

__global__ __launch_bounds__(1024) void rdf_finalize(
    const float* __restrict__ partials,
    int nblocks,
    const float* __restrict__ bins,
    float* __restrict__ out)
{
    __shared__ float red[128][8];
    __shared__ float raw[NBINS];
    __shared__ float ssum[2];

    const int t = threadIdx.x;
    const int c = t & 7;        // chunk 0..7
    const int b = t >> 3;       // bin 0..127

    if (b < NBINS) {
        const int chunk = nblocks >> 3;                // multiple of 4
        const float4* src = (const float4*)(partials + b * nblocks + c * chunk);
        const int n4 = chunk >> 2;
        float s = 0.0f;
        #pragma unroll 16
        for (int q = 0; q < n4; ++q) {
            const float4 v = src[q];
            s += v.x + v.y + v.z + v.w;
        }
        red[b][c] = s;
    }
    __syncthreads();

    if (t < NBINS) {
        float s = 0.0f;
        #pragma unroll
        for (int cc = 0; cc < 8; ++cc) s += red[t][cc];
        raw[t] = s;
    }
    __syncthreads();

    if (t < 128) {
        float v = (t < NBINS) ? raw[t] : 0.0f;
        #pragma unroll
        for (int o = 32; o > 0; o >>= 1) v += __shfl_down(v, o);
        if ((t & 63) == 0) ssum[t >> 6] = v;
    }
    __syncthreads();
    const float S = ssum[0] + ssum[1];

    if (t < NBINS) {
        const float cnt = raw[t] / S;
        out[t] = cnt;                                  // count
        const float b0 = bins[t], b1 = bins[t + 1];
        const float R  = bins[NBINS];                  // R_END = 7.5
        // rdf = cnt / (vol_bin / V) = cnt * R^3 / (b1^3 - b0^3)   (4pi/3 cancels)
        out[201 + t] = cnt * (R * R * R) / (b1 * b1 * b1 - b0 * b0 * b0);
    }
    if (t < NBINS + 1) {
        out[100 + t] = bins[t];                        // bins passthrough
    }
}

extern "C" void kernel_launch(void* const* d_in, const int* in_sizes, int n_in,
                              void* d_out, int out_size, void* d_ws, size_t ws_size,
                              hipStream_t stream) {
    const float* xyz     = (const float*)d_in[0];
    const float* cell    = (const float*)d_in[1];
    const float* bins    = (const float*)d_in[2];
    const float* offsets = (const float*)d_in[3];
    float* out      = (float*)d_out;
    float* partials = (float*)d_ws;

    int nblocks = 512;
    const int maxblocks = (int)(ws_size / (NBINS * sizeof(float)));
    if (nblocks > maxblocks) nblocks = maxblocks;
    nblocks &= ~31;                 // multiple of 32 so nblocks/8 is float4-aligned
    if (nblocks < 32) nblocks = 32;

    rdf_pairs<<<nblocks, 256, 0, stream>>>(xyz, cell, offsets, partials, nblocks);
    rdf_finalize<<<1, 1024, 0, stream>>>(partials, nblocks, bins, out);
}

// Round 3
// 47.906 us; speedup vs baseline: 4.9483x; 1.5179x over previous
//
#include <hip/hip_runtime.h>
#include <hip/hip_bf16.h>

// RDF with minimum-image PBC + Gaussian smearing, N=2048 atoms, 100 bins.
//
// Kernel 1 (rdf_pairs): exact upper-triangle enumeration via the cyclic
//   mapping q -> (i = q>>10, j = (i+1+(q&1023)) mod N): every slot is a
//   unique unordered pair (one predicate dedups the d==N/2 diagonal; the x2
//   pair weight cancels in count normalization). No input staging: xyz (24KB)
//   is L1-resident; offsets are analytic (k*width). Per-wave LDS histograms
//   (4x100 = 1.6KB). Smear = 11 INDEPENDENT __expf per pair (no serial
//   recurrence chain), predicated LDS atomicAdd. Partials transposed:
//   partials[bin*nblocks + block].
//
// Kernel 2 (rdf_finalize): 1 block x 1024 threads; 8 chunks x 128 bins,
//   float4 coalesced partial reduce, then normalize.
//   d_out = [count(100) | bins(101) | rdf(100)].

#define N_ATOMS 2048
#define HALF    1024
#define NBINS   100
#define WK      5        // +-5 bin widths: truncation exp(-12.5) ~ 4e-6 relative

__global__ __launch_bounds__(256) void rdf_pairs(
    const float* __restrict__ xyz,
    const float* __restrict__ cell,
    const float* __restrict__ offsets,
    float* __restrict__ partials,
    int nblocks)
{
    __shared__ float hist[4][NBINS];   // per-wave private histograms

    const int tid = threadIdx.x;
    if (tid < NBINS) {
        hist[0][tid] = 0.0f;
        hist[1][tid] = 0.0f;
        hist[2][tid] = 0.0f;
        hist[3][tid] = 0.0f;
    }
    __syncthreads();

    const float cx = cell[0], cy = cell[1], cz = cell[2];
    const float hcx = 0.5f * cx, hcy = 0.5f * cy, hcz = 0.5f * cz;

    const float width = offsets[1] - offsets[0];   // 7.5/99
    const float invw  = 1.0f / width;
    // Only dists with some bin k<=99 within +-WK matter: tu < 99+WK+1
    const float cutd  = (float)(NBINS - 1 + WK + 1) * width;   // 105*w = 7.954 < 8.0
    const float cut2  = cutd * cutd;

    float* const hw = hist[tid >> 6];

    const int total = N_ATOMS * HALF;          // 2^21 unique-pair slots
    const int gsize = nblocks * 256;

    for (int q = blockIdx.x * 256 + tid; q < total; q += gsize) {
        const int i = q >> 10;
        const int t = q & (HALF - 1);
        if (t == HALF - 1 && i >= HALF) continue;      // dedup d==N/2 diagonal
        const int j = (i + 1 + t) & (N_ATOMS - 1);

        // wave spans consecutive t within one i-row: i-loads broadcast,
        // j-loads stride-12B coalesced; all L1-resident (xyz = 24KB)
        const float xi = xyz[3 * i + 0];
        const float yi = xyz[3 * i + 1];
        const float zi = xyz[3 * i + 2];
        float dx = xyz[3 * j + 0] - xi;
        float dy = xyz[3 * j + 1] - yi;
        float dz = xyz[3 * j + 2] - zi;
        // minimum-image wrap (matches reference shift semantics)
        dx += (dx >= hcx) ? -cx : ((dx < -hcx) ? cx : 0.0f);
        dy += (dy >= hcy) ? -cy : ((dy < -hcy) ? cy : 0.0f);
        dz += (dz >= hcz) ? -cz : ((dz < -hcz) ? cz : 0.0f);

        const float dsq = dx * dx + dy * dy + dz * dz;
        if (dsq < cut2 && dsq != 0.0f) {
            const float tu  = sqrtf(dsq) * invw;    // distance in bin units
            const int   klo = (int)tu - WK;
            // 11 independent exps (no serial chain), predicated adds
            #pragma unroll
            for (int m = 0; m <= 2 * WK; ++m) {
                const int   k = klo + m;
                const float e = tu - (float)k;
                const float g = __expf(-0.5f * e * e);
                if (k >= 0 && k < NBINS) atomicAdd(&hw[k], g);
            }
        }
    }

    __syncthreads();
    if (tid < NBINS) {
        partials[tid * nblocks + blockIdx.x] =
            hist[0][tid] + hist[1][tid] + hist[2][tid] + hist[3][tid];
    }
}

__global__ __launch_bounds__(1024) void rdf_finalize(
    const float* __restrict__ partials,
    int nblocks,
    const float* __restrict__ bins,
    float* __restrict__ out)
{
    __shared__ float red[128][8];
    __shared__ float raw[NBINS];
    __shared__ float ssum[2];

    const int t = threadIdx.x;
    const int c = t & 7;        // chunk 0..7
    const int b = t >> 3;       // bin 0..127

    if (b < NBINS) {
        const int chunk = nblocks >> 3;                // multiple of 4
        const float4* src = (const float4*)(partials + b * nblocks + c * chunk);
        const int n4 = chunk >> 2;
        float s = 0.0f;
        #pragma unroll 8
        for (int q = 0; q < n4; ++q) {
            const float4 v = src[q];
            s += v.x + v.y + v.z + v.w;
        }
        red[b][c] = s;
    }
    __syncthreads();

    if (t < NBINS) {
        float s = 0.0f;
        #pragma unroll
        for (int cc = 0; cc < 8; ++cc) s += red[t][cc];
        raw[t] = s;
    }
    __syncthreads();

    if (t < 128) {
        float v = (t < NBINS) ? raw[t] : 0.0f;
        #pragma unroll
        for (int o = 32; o > 0; o >>= 1) v += __shfl_down(v, o);
        if ((t & 63) == 0) ssum[t >> 6] = v;
    }
    __syncthreads();
    const float S = ssum[0] + ssum[1];

    if (t < NBINS) {
        const float cnt = raw[t] / S;
        out[t] = cnt;                                  // count
        const float b0 = bins[t], b1 = bins[t + 1];
        const float R  = bins[NBINS];                  // R_END = 7.5
        // rdf = cnt / (vol_bin / V) = cnt * R^3 / (b1^3 - b0^3)   (4pi/3 cancels)
        out[201 + t] = cnt * (R * R * R) / (b1 * b1 * b1 - b0 * b0 * b0);
    }
    if (t < NBINS + 1) {
        out[100 + t] = bins[t];                        // bins passthrough
    }
}

extern "C" void kernel_launch(void* const* d_in, const int* in_sizes, int n_in,
                              void* d_out, int out_size, void* d_ws, size_t ws_size,
                              hipStream_t stream) {
    const float* xyz     = (const float*)d_in[0];
    const float* cell    = (const float*)d_in[1];
    const float* bins    = (const float*)d_in[2];
    const float* offsets = (const float*)d_in[3];
    float* out      = (float*)d_out;
    float* partials = (float*)d_ws;

    int nblocks = 1024;                 // 4 blocks/CU -> 16 waves/CU
    const int maxblocks = (int)(ws_size / (NBINS * sizeof(float)));
    if (nblocks > maxblocks) nblocks = maxblocks;
    nblocks &= ~31;                     // multiple of 32: chunk float4-aligned
    if (nblocks < 32) nblocks = 32;

    rdf_pairs<<<nblocks, 256, 0, stream>>>(xyz, cell, offsets, partials, nblocks);
    rdf_finalize<<<1, 1024, 0, stream>>>(partials, nblocks, bins, out);
}

// Round 4
// 20.521 us; speedup vs baseline: 11.5516x; 2.3345x over previous
//
#include <hip/hip_runtime.h>
#include <hip/hip_bf16.h>

// RDF with minimum-image PBC + Gaussian smearing, N=2048 atoms, 100 bins.
//
// Round-4 structure: the Gaussian smear is a linear convolution over
// distance, so the hot pair loop does ONE LDS atomicAdd(1.0f) into a FINE
// distance histogram (S=17 sub-bins per coarse bin; counts are integers in
// f32 -> order-independent, deterministic). A per-block epilogue convolves
// the fine histogram with a 103-tap Gaussian table (fine stride 17 is
// coprime with 32 LDS banks -> conflict-free strided reads). Pairs with
// dist < 8 bin-units (~200 total) take an EXACT direct-smear path into
// coarse bins 0..11, where low statistics would otherwise amplify
// quantization error through the tiny-shell-volume rdf normalization.
//
// Kernel 2 (rdf_finalize): 1 block x 1024 threads reduces the transposed
// per-block partials, normalizes, writes
// d_out = [count(100) | bins(101) | rdf(100)].

#define N_ATOMS 2048
#define HALF    1024
#define NBINS   100
#define S_FINE  17          // fine sub-bins per coarse bin (coprime with 32)
#define FBINS   1744        // > 102.5 * 17 = 1742.5
#define TAPS    103         // 2*3*17 + 1  (window +-3 bin widths)
#define NDIR    12          // exact direct-path coarse bins 0..11
#define TLOW    8.0f        // bin-units: below this, take the exact path

__global__ __launch_bounds__(512) void rdf_pairs(
    const float* __restrict__ xyz,
    const float* __restrict__ cell,
    const float* __restrict__ offsets,
    float* __restrict__ partials,
    int nblocks)
{
    __shared__ float fine[FBINS];       // fine distance histogram (counts)
    __shared__ float wtab[TAPS];        // Gaussian taps
    __shared__ float conv[NBINS][4];    // per-chunk convolution partials
    __shared__ float cd[16];            // exact direct-path coarse bins

    const int tid = threadIdx.x;

    for (int a = tid; a < FBINS; a += 512) fine[a] = 0.0f;
    if (tid < 16)   cd[tid] = 0.0f;
    if (tid < TAPS) {
        const float u = ((float)tid - 50.5f) * (1.0f / (float)S_FINE);
        wtab[tid] = __expf(-0.5f * u * u);
    }
    __syncthreads();

    const float cx = cell[0], cy = cell[1], cz = cell[2];
    const float hcx = 0.5f * cx, hcy = 0.5f * cy, hcz = 0.5f * cz;

    const float width = offsets[1] - offsets[0];   // 7.5/99
    const float invw  = 1.0f / width;
    // quantized-path cut: tu < 102.5 bin-units (beyond: no bin k<=99 within
    // the +-3 window; reference's extra shell contributes <= e^-6 tails that
    // cancel in normalization)
    const float cutd  = 102.5f * width;            // 7.765 < CUTOFF_B = 8.0
    const float cut2  = cutd * cutd;
    const float finesc = invw * (float)S_FINE;     // dist -> fine-bin units

    const int total = N_ATOMS * HALF;              // 2^21 unique-pair slots
    const int gsize = nblocks * 512;

    for (int q = blockIdx.x * 512 + tid; q < total; q += gsize) {
        const int i = q >> 10;
        const int t = q & (HALF - 1);
        if (t == HALF - 1 && i >= HALF) continue;  // dedup d==N/2 diagonal
        const int j = (i + 1 + t) & (N_ATOMS - 1);

        // i-loads ~wave-uniform (broadcast), j-loads stride-12B coalesced;
        // xyz = 24KB -> L1-resident, no staging needed
        const float xi = xyz[3 * i + 0];
        const float yi = xyz[3 * i + 1];
        const float zi = xyz[3 * i + 2];
        float dx = xyz[3 * j + 0] - xi;
        float dy = xyz[3 * j + 1] - yi;
        float dz = xyz[3 * j + 2] - zi;
        // minimum-image wrap (matches reference shift semantics)
        dx += (dx >= hcx) ? -cx : ((dx < -hcx) ? cx : 0.0f);
        dy += (dy >= hcy) ? -cy : ((dy < -hcy) ? cy : 0.0f);
        dz += (dz >= hcz) ? -cz : ((dz < -hcz) ? cz : 0.0f);

        const float dsq = dx * dx + dy * dy + dz * dz;
        if (dsq < cut2 && dsq != 0.0f) {
            const float tu = sqrtf(dsq) * invw;    // distance in bin units
            if (tu >= TLOW) {
                // ONE atomic per pair; integer counts in f32 => exact,
                // order-independent; 64 lanes scatter over 1744 bins =>
                // conflicts rare
                atomicAdd(&fine[(int)(sqrtf(dsq) * finesc)], 1.0f);
            } else {
                // exact path for low bins (~200 pairs device-wide): full
                // window k=0..11, no quantization
                int khi = (int)tu + 4; if (khi > NDIR - 1) khi = NDIR - 1;
                for (int k = 0; k <= khi; ++k) {
                    const float e = tu - (float)k;
                    atomicAdd(&cd[k], __expf(-0.5f * e * e));
                }
            }
        }
    }

    __syncthreads();

    // Convolve fine histogram with Gaussian taps: coarse[k] = sum_d
    // wtab[d+51] * fine[17k+d], d in [-51,51]. 400 threads: k = t>>2,
    // chunk c = t&3 (26/26/26/25 taps). Stride-17 reads are bank-conflict
    // free (gcd(17,32)=1).
    if (tid < 400) {
        const int k = tid >> 2;
        const int c = tid & 3;
        const int m0 = c * 26;
        const int mcnt = (c == 3) ? 25 : 26;
        float s = 0.0f;
        for (int mm = 0; mm < mcnt; ++mm) {
            const int m = m0 + mm;
            const int f = S_FINE * k + m - 51;     // max 17*99+51 = 1734
            if (f >= 0) s += wtab[m] * fine[f];
        }
        conv[k][c] = s;
    }
    __syncthreads();

    if (tid < NBINS) {
        float raw = conv[tid][0] + conv[tid][1] + conv[tid][2] + conv[tid][3];
        if (tid < NDIR) raw += cd[tid];
        partials[tid * nblocks + blockIdx.x] = raw;   // transposed
    }
}

__global__ __launch_bounds__(1024) void rdf_finalize(
    const float* __restrict__ partials,
    int nblocks,
    const float* __restrict__ bins,
    float* __restrict__ out)
{
    __shared__ float red[128][8];
    __shared__ float raw[NBINS];
    __shared__ float ssum[2];

    const int t = threadIdx.x;
    const int c = t & 7;        // chunk 0..7
    const int b = t >> 3;       // bin 0..127

    if (b < NBINS) {
        const int chunk = nblocks >> 3;                // multiple of 4
        const float4* src = (const float4*)(partials + b * nblocks + c * chunk);
        const int n4 = chunk >> 2;
        float s = 0.0f;
        #pragma unroll 8
        for (int q = 0; q < n4; ++q) {
            const float4 v = src[q];
            s += v.x + v.y + v.z + v.w;
        }
        red[b][c] = s;
    }
    __syncthreads();

    if (t < NBINS) {
        float s = 0.0f;
        #pragma unroll
        for (int cc = 0; cc < 8; ++cc) s += red[t][cc];
        raw[t] = s;
    }
    __syncthreads();

    if (t < 128) {
        float v = (t < NBINS) ? raw[t] : 0.0f;
        #pragma unroll
        for (int o = 32; o > 0; o >>= 1) v += __shfl_down(v, o);
        if ((t & 63) == 0) ssum[t >> 6] = v;
    }
    __syncthreads();
    const float S = ssum[0] + ssum[1];

    if (t < NBINS) {
        const float cnt = raw[t] / S;
        out[t] = cnt;                                  // count
        const float b0 = bins[t], b1 = bins[t + 1];
        const float R  = bins[NBINS];                  // R_END = 7.5
        // rdf = cnt / (vol_bin / V) = cnt * R^3 / (b1^3 - b0^3)  (4pi/3 cancels)
        out[201 + t] = cnt * (R * R * R) / (b1 * b1 * b1 - b0 * b0 * b0);
    }
    if (t < NBINS + 1) {
        out[100 + t] = bins[t];                        // bins passthrough
    }
}

extern "C" void kernel_launch(void* const* d_in, const int* in_sizes, int n_in,
                              void* d_out, int out_size, void* d_ws, size_t ws_size,
                              hipStream_t stream) {
    const float* xyz     = (const float*)d_in[0];
    const float* cell    = (const float*)d_in[1];
    const float* bins    = (const float*)d_in[2];
    const float* offsets = (const float*)d_in[3];
    float* out      = (float*)d_out;
    float* partials = (float*)d_ws;

    int nblocks = 256;                  // 1 block/CU x 512 threads = 8 waves/CU
    const int maxblocks = (int)(ws_size / (NBINS * sizeof(float)));
    if (nblocks > maxblocks) nblocks = maxblocks;
    nblocks &= ~31;                     // multiple of 32: chunk float4-aligned
    if (nblocks < 32) nblocks = 32;

    rdf_pairs<<<nblocks, 512, 0, stream>>>(xyz, cell, offsets, partials, nblocks);
    rdf_finalize<<<1, 1024, 0, stream>>>(partials, nblocks, bins, out);
}